// Round 7
// baseline (164.048 us; speedup 1.0000x reference)
//
#include <hip/hip_runtime.h>

#define NB 128
#define NA 2
#define NH 128
#define NW 128
#define PLANE (NH * NW)            // 16384 floats per channel plane
#define OBJ_SCALE 5.0f
#define NBLK 1024                  // 4 blocks/CU, all co-resident
#define POISON 0xAAAAAAAAu         // harness re-poisons d_ws to 0xAA each launch

// NOTE (r6 post-mortem): __builtin_nontemporal_load here was a 2.2x
// REGRESSION (64us vs 27us, FETCH_SIZE unchanged) — nt bypasses L1/L2
// allocation so every load pays L3/HBM-class latency on a half-cache-warm
// input. Plain loads restored.

// Fast sigmoid: v_exp + v_rcp (~1ulp) — no v_div sequences.
__device__ __forceinline__ float sigm(float v) {
    return __builtin_amdgcn_rcpf(1.0f + __expf(-v));
}

// Per-batch GT-box constants + best-anchor selection (tiny inputs, L1-hit,
// wave-uniform b -> scalar loads). Full-precision divides kept (argmax).
__device__ __forceinline__ void batch_const(const float* __restrict__ target,
                                            const float* __restrict__ anchors,
                                            int b,
                                            float& gx, float& gy, float& gw, float& gh,
                                            int& bn, int& gxi, int& gyi) {
    float t0 = target[b * 4 + 0], t1 = target[b * 4 + 1];
    float t2 = target[b * 4 + 2], t3 = target[b * 4 + 3];
    gx = t0 * (float)NW;
    gy = t1 * (float)NH;
    gw = t2 * (float)NW;
    gh = t3 * (float)NH;
    float a0w = anchors[0], a0h = anchors[1];
    float a1w = anchors[2], a1h = anchors[3];
    float i0 = fminf(gw, a0w) * fminf(gh, a0h);
    float u0 = gw * gh + 1e-16f + a0w * a0h - i0;
    float i1 = fminf(gw, a1w) * fminf(gh, a1h);
    float u1 = gw * gh + 1e-16f + a1w * a1h - i1;
    bn  = (i1 / u1 > i0 / u0) ? 1 : 0;   // argmax picks FIRST max
    gxi = (int)gx;   // gt_x in (12.8, 115.2): trunc == floor, in-bounds
    gyi = (int)gy;
}

// Single fused kernel. Dense phase: 1024 blocks x 256 threads x 16 cells.
// Finalize: per-block partials to d_ws + agent-release fence + ticket atomic;
// LAST block acquires and reduces the 1024 partials + 128 selected-cell
// losses (no 2nd dispatch). Ticket starts at the deterministic 0xAAAAAAAA
// poison; zeroed start also accepted.
__global__ __launch_bounds__(256) void region_fused(
        const float* __restrict__ out,
        const float* __restrict__ target,
        const float* __restrict__ anchors,
        float* __restrict__ psum,
        unsigned int* __restrict__ pcnt,
        unsigned int* __restrict__ ticket,
        float* __restrict__ loss_out) {
    int tid = threadIdx.x;
    int bid = blockIdx.x;
    int slab = bid >> 2;           // (b, a) pair, 0..255
    int part = bid & 3;            // quarter of the 16384-cell plane
    int b = slab >> 1, a = slab & 1;

    float gx, gy, gw, gh; int bn, gxi, gyi;
    batch_const(target, anchors, b, gx, gy, gw, gh, bn, gxi, gyi);
    float aw = anchors[a * 2 + 0];
    float ah = anchors[a * 2 + 1];

    const float* pb = out + (size_t)(b * 10 + a * 5) * PLANE + part * 4096 + tid * 4;

    // prime the pipeline: sweep 0 loads
    float4 cx  = *(const float4*)(pb);
    float4 cy  = *(const float4*)(pb + 1 * PLANE);
    float4 cw4 = *(const float4*)(pb + 2 * PLANE);
    float4 ch4 = *(const float4*)(pb + 3 * PLANE);
    float4 cc  = *(const float4*)(pb + 4 * PLANE);

    float gxm = gx - gw * 0.5f, gxM = gx + gw * 0.5f;
    float gym = gy - gh * 0.5f, gyM = gy + gh * 0.5f;
    float garea = gw * gh;
    bool a_sel = (a == bn);

    float lsum = 0.0f;
    int   lcnt = 0;

#pragma unroll
    for (int s = 0; s < 4; ++s) {
        float4 nx, ny, nw4, nh4, nc;
        if (s < 3) {   // depth-1 register prefetch of next sweep
            const float* pn = pb + (s + 1) * 1024;
            nx  = *(const float4*)(pn);
            ny  = *(const float4*)(pn + 1 * PLANE);
            nw4 = *(const float4*)(pn + 2 * PLANE);
            nh4 = *(const float4*)(pn + 3 * PLANE);
            nc  = *(const float4*)(pn + 4 * PLANE);
        }

        int pos0 = part * 4096 + s * 1024 + tid * 4;
        int i  = pos0 >> 7;         // row, constant across e (tid*4 <= 1020)
        int j0 = pos0 & 127;
        float fi = (float)i;
        bool row_sel = a_sel && (i == gyi);

        const float* fx = (const float*)&cx;
        const float* fy = (const float*)&cy;
        const float* fw = (const float*)&cw4;
        const float* fh = (const float*)&ch4;
        const float* fc = (const float*)&cc;

#pragma unroll
        for (int e = 0; e < 4; ++e) {
            float px = sigm(fx[e]) + (float)(j0 + e);
            float py = sigm(fy[e]) + fi;
            float pw = __expf(fw[e]) * aw;
            float ph = __expf(fh[e]) * ah;
            float cf = sigm(fc[e]);

            float pwh = pw * 0.5f, phh = ph * 0.5f;
            float mx = fminf(px - pwh, gxm);
            float Mx = fmaxf(px + pwh, gxM);
            float my = fminf(py - phh, gym);
            float My = fmaxf(py + phh, gyM);
            float cw = pw + gw - (Mx - mx);
            float ch = ph + gh - (My - my);
            float carea = cw * ch;
            float uarea = pw * ph + garea - carea;
            // divide-free iou<=0.6: uarea >= garea > 40 always;
            // no-overlap => iou=0 => noobj true.
            bool noobj = (cw <= 0.0f) || (ch <= 0.0f) ||
                         (carea <= 0.6f * uarea);
            noobj = noobj && !(row_sel && (j0 + e) == gxi);
            if (noobj) { lsum += cf * cf; lcnt += 1; }
        }

        if (s < 3) { cx = nx; cy = ny; cw4 = nw4; ch4 = nh4; cc = nc; }
    }

    // ---- block reduction: wave64 shuffle tree, then LDS across 4 waves ----
#pragma unroll
    for (int off = 32; off > 0; off >>= 1) {
        lsum += __shfl_down(lsum, off);
        lcnt += __shfl_down(lcnt, off);
    }
    __shared__ float ssum[4];
    __shared__ int   scnt[4];
    __shared__ unsigned int islast;
    int wid = tid >> 6, lane = tid & 63;
    if (lane == 0) { ssum[wid] = lsum; scnt[wid] = lcnt; }
    __syncthreads();

    if (tid == 0) {
        psum[bid] = ssum[0] + ssum[1] + ssum[2] + ssum[3];
        pcnt[bid] = (unsigned int)(scnt[0] + scnt[1] + scnt[2] + scnt[3]);
        __threadfence();   // agent release: partials visible device-wide
        unsigned int old = atomicAdd(ticket, 1u);
        islast = ((old - POISON) == (NBLK - 1u)) || (old == (NBLK - 1u));
    }
    __syncthreads();
    if (!islast) return;

    // ---- last block: acquire, then reduce all partials + batch terms ----
    __threadfence();       // agent acquire

    float s = 0.0f;
    unsigned int c = 0;
#pragma unroll
    for (int k = 0; k < NBLK / 256; ++k) {
        s += psum[tid + k * 256];
        c += pcnt[tid + k * 256];
    }

    float v = 0.0f;
    if (tid < NB) {
        int bb = tid;
        float fgx, fgy, fgw, fgh; int fbn, fgxi, fgyi;
        batch_const(target, anchors, bb, fgx, fgy, fgw, fgh, fbn, fgxi, fgyi);
        float tx = fgx - floorf(fgx);
        float ty = fgy - floorf(fgy);
        float baw = anchors[fbn * 2 + 0];
        float bah = anchors[fbn * 2 + 1];
        float tw = __logf(fgw / baw + 1e-16f);
        float th = __logf(fgh / bah + 1e-16f);
        float scale = 2.0f - target[bb * 4 + 2] * target[bb * 4 + 3];

        size_t base = (size_t)(bb * 10 + fbn * 5) * PLANE
                    + (size_t)fgyi * NW + (size_t)fgxi;
        float xs = sigm(out[base]);
        float ys = sigm(out[base + 1 * PLANE]);
        float wr = out[base + 2 * PLANE];
        float hr = out[base + 3 * PLANE];
        float cs = sigm(out[base + 4 * PLANE]);

        float dx = (xs - tx) * scale;
        float dy = (ys - ty) * scale;
        float dw = (wr - tw) * scale;
        float dh = (hr - th) * scale;
        float dc = cs - 1.0f;
        v = dx * dx + dy * dy + dw * dw + dh * dh + OBJ_SCALE * dc * dc;
    }

#pragma unroll
    for (int off = 32; off > 0; off >>= 1) {
        s += __shfl_down(s, off);
        c += __shfl_down(c, off);
        v += __shfl_down(v, off);
    }
    __shared__ float fs[4];
    __shared__ unsigned int fcn[4];
    __shared__ float fv[4];
    if (lane == 0) { fs[wid] = s; fcn[wid] = c; fv[wid] = v; }
    __syncthreads();
    if (tid == 0) {
        float S = fs[0] + fs[1] + fs[2] + fs[3];
        unsigned int C = fcn[0] + fcn[1] + fcn[2] + fcn[3];
        float V = fv[0] + fv[1] + fv[2] + fv[3];
        loss_out[0] = V * (1.0f / (float)NB) + S / (float)C;
    }
}

extern "C" void kernel_launch(void* const* d_in, const int* in_sizes, int n_in,
                              void* d_out, int out_size, void* d_ws, size_t ws_size,
                              hipStream_t stream) {
    const float* output  = (const float*)d_in[0];   // (128, 10, 128, 128) fp32
    const float* target  = (const float*)d_in[1];   // (128, 4)
    const float* anchors = (const float*)d_in[2];   // (2, 2)
    float* loss = (float*)d_out;

    // d_ws layout: [0,4K) float psum[1024]; [4K,8K) uint pcnt[1024];
    // [8K] uint ticket (starts at the harness's 0xAAAAAAAA poison each
    // launch — last-block detection is relative to that; zeroed start also
    // accepted). psum/pcnt slots all written unconditionally.
    float* psum = (float*)d_ws;
    unsigned int* pcnt = (unsigned int*)((char*)d_ws + 4096);
    unsigned int* ticket = (unsigned int*)((char*)d_ws + 8192);

    region_fused<<<NBLK, 256, 0, stream>>>(output, target, anchors,
                                           psum, pcnt, ticket, loss);
}

// Round 8
// 123.012 us; speedup vs baseline: 1.3336x; 1.3336x over previous
//
#include <hip/hip_runtime.h>

#define NB 128
#define NA 2
#define NH 128
#define NW 128
#define PLANE (NH * NW)            // 16384 floats per channel plane
#define OBJ_SCALE 5.0f
#define NBLK 1024                  // 4 blocks/CU, all co-resident

// r6/r7 post-mortem: single-kernel last-block-done fusion REGRESSED 27->64-75us
// (agent-scope __threadfence per block = per-XCD L2 writeback+invalidate,
// staggered across the kernel tail, killing cache-warm input for running
// blocks; + 1024 same-address ticket atomics). Two-kernel structure restored.
// r6: __builtin_nontemporal_load also regressed (bypasses L1/L2 allocation on
// a half-cache-warm input). Plain float4 loads.

// Fast sigmoid: v_exp + v_rcp (~1ulp) — no v_div sequences.
__device__ __forceinline__ float sigm(float v) {
    return __builtin_amdgcn_rcpf(1.0f + __expf(-v));
}

// Per-batch GT-box constants + best-anchor selection (tiny inputs, L1-hit,
// wave-uniform b -> scalar loads). Full-precision divides kept (argmax).
__device__ __forceinline__ void batch_const(const float* __restrict__ target,
                                            const float* __restrict__ anchors,
                                            int b,
                                            float& gx, float& gy, float& gw, float& gh,
                                            int& bn, int& gxi, int& gyi) {
    float t0 = target[b * 4 + 0], t1 = target[b * 4 + 1];
    float t2 = target[b * 4 + 2], t3 = target[b * 4 + 3];
    gx = t0 * (float)NW;
    gy = t1 * (float)NH;
    gw = t2 * (float)NW;
    gh = t3 * (float)NH;
    float a0w = anchors[0], a0h = anchors[1];
    float a1w = anchors[2], a1h = anchors[3];
    float i0 = fminf(gw, a0w) * fminf(gh, a0h);
    float u0 = gw * gh + 1e-16f + a0w * a0h - i0;
    float i1 = fminf(gw, a1w) * fminf(gh, a1h);
    float u1 = gw * gh + 1e-16f + a1w * a1h - i1;
    bn  = (i1 / u1 > i0 / u0) ? 1 : 0;   // argmax picks FIRST max
    gxi = (int)gx;   // gt_x in (12.8, 115.2): trunc == floor, in-bounds
    gyi = (int)gy;
}

// Dense pass. 1024 blocks x 256 threads x 16 cells = 4,194,304 cells.
// 4 blocks/CU co-resident; depth-1 register prefetch across 4 sweeps of
// 5 float4 loads. Divide-free inner loop (iou<=0.6 as carea<=0.6*uarea;
// uarea >= garea > 40 always; no-overlap => noobj true).
// Per-block partial writes, no same-address atomics (r1 postmortem).
__global__ __launch_bounds__(256) void region_main(
        const float* __restrict__ out,
        const float* __restrict__ target,
        const float* __restrict__ anchors,
        float* __restrict__ psum,
        unsigned int* __restrict__ pcnt) {
    int tid = threadIdx.x;
    int bid = blockIdx.x;
    int slab = bid >> 2;           // (b, a) pair, 0..255
    int part = bid & 3;            // quarter of the 16384-cell plane
    int b = slab >> 1, a = slab & 1;

    float gx, gy, gw, gh; int bn, gxi, gyi;
    batch_const(target, anchors, b, gx, gy, gw, gh, bn, gxi, gyi);
    float aw = anchors[a * 2 + 0];
    float ah = anchors[a * 2 + 1];

    const float* pb = out + (size_t)(b * 10 + a * 5) * PLANE + part * 4096 + tid * 4;

    // prime the pipeline: sweep 0 loads
    float4 cx  = *(const float4*)(pb);
    float4 cy  = *(const float4*)(pb + 1 * PLANE);
    float4 cw4 = *(const float4*)(pb + 2 * PLANE);
    float4 ch4 = *(const float4*)(pb + 3 * PLANE);
    float4 cc  = *(const float4*)(pb + 4 * PLANE);

    float gxm = gx - gw * 0.5f, gxM = gx + gw * 0.5f;
    float gym = gy - gh * 0.5f, gyM = gy + gh * 0.5f;
    float garea = gw * gh;
    bool a_sel = (a == bn);

    float lsum = 0.0f;
    int   lcnt = 0;

#pragma unroll
    for (int s = 0; s < 4; ++s) {
        float4 nx, ny, nw4, nh4, nc;
        if (s < 3) {   // depth-1 register prefetch of next sweep
            const float* pn = pb + (s + 1) * 1024;
            nx  = *(const float4*)(pn);
            ny  = *(const float4*)(pn + 1 * PLANE);
            nw4 = *(const float4*)(pn + 2 * PLANE);
            nh4 = *(const float4*)(pn + 3 * PLANE);
            nc  = *(const float4*)(pn + 4 * PLANE);
        }

        int pos0 = part * 4096 + s * 1024 + tid * 4;
        int i  = pos0 >> 7;         // row, constant across e (tid*4 <= 1020)
        int j0 = pos0 & 127;
        float fi = (float)i;
        bool row_sel = a_sel && (i == gyi);

        const float* fx = (const float*)&cx;
        const float* fy = (const float*)&cy;
        const float* fw = (const float*)&cw4;
        const float* fh = (const float*)&ch4;
        const float* fc = (const float*)&cc;

#pragma unroll
        for (int e = 0; e < 4; ++e) {
            float px = sigm(fx[e]) + (float)(j0 + e);
            float py = sigm(fy[e]) + fi;
            float pw = __expf(fw[e]) * aw;
            float ph = __expf(fh[e]) * ah;
            float cf = sigm(fc[e]);

            float pwh = pw * 0.5f, phh = ph * 0.5f;
            float mx = fminf(px - pwh, gxm);
            float Mx = fmaxf(px + pwh, gxM);
            float my = fminf(py - phh, gym);
            float My = fmaxf(py + phh, gyM);
            float cw = pw + gw - (Mx - mx);
            float ch = ph + gh - (My - my);
            float carea = cw * ch;
            float uarea = pw * ph + garea - carea;
            bool noobj = (cw <= 0.0f) || (ch <= 0.0f) ||
                         (carea <= 0.6f * uarea);
            noobj = noobj && !(row_sel && (j0 + e) == gxi);
            if (noobj) { lsum += cf * cf; lcnt += 1; }
        }

        if (s < 3) { cx = nx; cy = ny; cw4 = nw4; ch4 = nh4; cc = nc; }
    }

    // wave64 shuffle tree, then LDS across 4 waves, one store per block
#pragma unroll
    for (int off = 32; off > 0; off >>= 1) {
        lsum += __shfl_down(lsum, off);
        lcnt += __shfl_down(lcnt, off);
    }
    __shared__ float ssum[4];
    __shared__ int   scnt[4];
    int wid = tid >> 6, lane = tid & 63;
    if (lane == 0) { ssum[wid] = lsum; scnt[wid] = lcnt; }
    __syncthreads();
    if (tid == 0) {
        psum[bid] = ssum[0] + ssum[1] + ssum[2] + ssum[3];
        pcnt[bid] = (unsigned int)(scnt[0] + scnt[1] + scnt[2] + scnt[3]);
    }
}

// Final: reduce 1024 partials + 128 selected-cell losses. 1 block, 1024 thr.
__global__ __launch_bounds__(1024) void region_final(
        const float* __restrict__ out,
        const float* __restrict__ target,
        const float* __restrict__ anchors,
        const float* __restrict__ psum,
        const unsigned int* __restrict__ pcnt,
        float* __restrict__ loss_out) {
    int t = threadIdx.x;
    float s = psum[t];
    unsigned int c = pcnt[t];

    float v = 0.0f;
    if (t < NB) {
        int b = t;
        float gx, gy, gw, gh; int bn, gxi, gyi;
        batch_const(target, anchors, b, gx, gy, gw, gh, bn, gxi, gyi);
        float tx = gx - floorf(gx);
        float ty = gy - floorf(gy);
        float aw = anchors[bn * 2 + 0];
        float ah = anchors[bn * 2 + 1];
        float tw = __logf(gw / aw + 1e-16f);
        float th = __logf(gh / ah + 1e-16f);
        float scale = 2.0f - target[b * 4 + 2] * target[b * 4 + 3];

        size_t base = (size_t)(b * 10 + bn * 5) * PLANE + (size_t)gyi * NW + (size_t)gxi;
        float xs = sigm(out[base]);
        float ys = sigm(out[base + 1 * PLANE]);
        float wr = out[base + 2 * PLANE];
        float hr = out[base + 3 * PLANE];
        float cs = sigm(out[base + 4 * PLANE]);

        float dx = (xs - tx) * scale;
        float dy = (ys - ty) * scale;
        float dw = (wr - tw) * scale;
        float dh = (hr - th) * scale;
        float dc = cs - 1.0f;
        v = dx * dx + dy * dy + dw * dw + dh * dh + OBJ_SCALE * dc * dc;
    }

#pragma unroll
    for (int off = 32; off > 0; off >>= 1) {
        s += __shfl_down(s, off);
        c += __shfl_down(c, off);
        v += __shfl_down(v, off);
    }
    __shared__ float ss[16];
    __shared__ unsigned int sc[16];
    __shared__ float sv[16];
    int wid = t >> 6, lane = t & 63;
    if (lane == 0) { ss[wid] = s; sc[wid] = c; sv[wid] = v; }
    __syncthreads();
    if (t < 16) {
        s = ss[t]; c = sc[t]; v = sv[t];
#pragma unroll
        for (int off = 8; off > 0; off >>= 1) {
            s += __shfl_down(s, off);
            c += __shfl_down(c, off);
            v += __shfl_down(v, off);
        }
        if (t == 0)
            loss_out[0] = v * (1.0f / (float)NB) + s / (float)c;
    }
}

extern "C" void kernel_launch(void* const* d_in, const int* in_sizes, int n_in,
                              void* d_out, int out_size, void* d_ws, size_t ws_size,
                              hipStream_t stream) {
    const float* output  = (const float*)d_in[0];   // (128, 10, 128, 128) fp32
    const float* target  = (const float*)d_in[1];   // (128, 4)
    const float* anchors = (const float*)d_in[2];   // (2, 2)
    float* loss = (float*)d_out;

    // d_ws layout: [0,4K) float psum[1024]; [4K,8K) uint pcnt[1024].
    // Every slot written unconditionally -> no memset of poisoned ws needed.
    float* psum = (float*)d_ws;
    unsigned int* pcnt = (unsigned int*)((char*)d_ws + NBLK * sizeof(float));

    region_main<<<NBLK, 256, 0, stream>>>(output, target, anchors, psum, pcnt);
    region_final<<<1, 1024, 0, stream>>>(output, target, anchors, psum, pcnt, loss);
}